// Round 1
// baseline (226.152 us; speedup 1.0000x reference)
//
#include <hip/hip_runtime.h>
#include <hip/hip_bf16.h>

typedef float f32x4 __attribute__((ext_vector_type(4)));
typedef short bf16x8 __attribute__((ext_vector_type(8)));
typedef unsigned short us8 __attribute__((ext_vector_type(8)));

__device__ __forceinline__ unsigned short f2bf(float f) {
  union { float f; unsigned u; } v; v.f = f;
  return (unsigned short)((v.u + 0x8000u) >> 16);   // round-half-up bf16
}
__device__ __forceinline__ float bf2f(unsigned short u) {
  union { unsigned u; float f; } v; v.u = ((unsigned)u) << 16;
  return v.f;
}

// ---------------------------------------------------------------------------
// Kernel 1: VmatT[b][n][p] (bf16), n = c*16+u*4+v (256), p = pi*64+pj (4096)
// VmatT[b,n,p] = x[b, c, clamp(2*pi+u-1), clamp(2*pj+v-1)]   (replication pad)
// Stored n-major so the GEMM B-fragment read is contiguous in k(=p).
// ---------------------------------------------------------------------------
__global__ __launch_bounds__(256) void prep_vmat(const float* __restrict__ x,
                                                 unsigned short* __restrict__ vmatT) {
  int t = blockIdx.x * 256 + threadIdx.x;     // 1,048,576 threads, 8 elems each
  int pc = t & 511;                            // p-chunk of 8
  int n  = (t >> 9) & 255;
  int b  = t >> 17;
  int c = n >> 4, u = (n >> 2) & 3, v = n & 3;
  int pi = pc >> 3;
  int pj0 = (pc & 7) << 3;
  int row = 2 * pi + u - 1;
  row = row < 0 ? 0 : (row > 127 ? 127 : row);
  const float* xr = x + ((size_t)(b * 16 + c) * 128 + row) * 128;
  us8 o;
#pragma unroll
  for (int e = 0; e < 8; ++e) {
    int col = 2 * (pj0 + e) + v - 1;
    col = col < 0 ? 0 : (col > 127 ? 127 : col);
    o[e] = f2bf(xr[col]);
  }
  *reinterpret_cast<us8*>(vmatT + (size_t)t * 8) = o;
}

// ---------------------------------------------------------------------------
// Kernel 2: A[b][q][n] (bf16) = sum_p scores[b][q][p] * VmatT[b][n][p]
// M=4096 (q), N=256 (all n in one block), K=4096. BQ=64, BK=32.
// 256 threads = 4 waves; wave w owns cols w*64..w*64+63; tile 64x64 per wave
// (4x4 fragments of 16x16x32). Double-buffered LDS (40 KB static).
// scores staged fp32->bf16 through registers; VmatT via global_load_lds(16B).
// ---------------------------------------------------------------------------
__global__ __launch_bounds__(256) void gemm_scores_vmat(
    const float* __restrict__ scores,
    const unsigned short* __restrict__ vmatT,
    unsigned short* __restrict__ Amat) {
  __shared__ unsigned short lds[2][10240];   // per buf: A[64][32] then B[256][32]

  // XCD swizzle: 512 blocks, batch k's 64 blocks land on XCD k (VmatT slice L2-fits)
  int bid = blockIdx.x;
  int nb = ((bid & 7) << 6) | (bid >> 3);
  int batch = nb >> 6;
  int qb = (nb & 63) << 6;

  const int t = threadIdx.x;
  const int lane = t & 63;
  const int wn = t >> 6;                 // wave id = N-quadrant
  const int l15 = lane & 15, l16 = lane >> 4;

  const float* S = scores + ((size_t)batch * 4096 + qb) * 4096;
  const unsigned short* Vb = vmatT + (size_t)batch * 256 * 4096;

  // A staging: thread t -> row r=t>>2 (of 64), slot sl=t&3 (8 floats = 32B)
  const float* aSrc = S + (size_t)(t >> 2) * 4096 + (t & 3) * 8;
  const int aDst = t * 8;                // elems, linear [r][sl*8]
  // B staging: 4 chunks/thread, chunk c -> row n=c>>2 (of 256), slot c&3
  const unsigned short* bSrc[4];
  int bDst[4];
#pragma unroll
  for (int i = 0; i < 4; ++i) {
    int c = t + i * 256;
    bSrc[i] = Vb + (size_t)(c >> 2) * 4096 + (c & 3) * 8;
    bDst[i] = 2048 + c * 8;
  }

  f32x4 acc[4][4];
#pragma unroll
  for (int mi = 0; mi < 4; ++mi)
#pragma unroll
    for (int ni = 0; ni < 4; ++ni)
      acc[mi][ni] = (f32x4){0.f, 0.f, 0.f, 0.f};

  // prologue: stage kt=0 into buf 0
  {
    f32x4 av0 = *(const f32x4*)(aSrc);
    f32x4 av1 = *(const f32x4*)(aSrc + 4);
#pragma unroll
    for (int i = 0; i < 4; ++i)
      __builtin_amdgcn_global_load_lds(
          (const __attribute__((address_space(1))) void*)(bSrc[i]),
          (__attribute__((address_space(3))) void*)&lds[0][bDst[i]], 16, 0, 0);
    us8 p;
#pragma unroll
    for (int e = 0; e < 4; ++e) { p[e] = f2bf(av0[e]); p[e + 4] = f2bf(av1[e]); }
    *(us8*)&lds[0][aDst] = p;
  }
  __syncthreads();

  int buf = 0;
  for (int kt = 0; kt < 128; ++kt) {
    f32x4 av0, av1;
    const bool nx = (kt + 1 < 128);
    if (nx) {                                   // issue next-tile loads first
      av0 = *(const f32x4*)(aSrc + (kt + 1) * 32);
      av1 = *(const f32x4*)(aSrc + (kt + 1) * 32 + 4);
#pragma unroll
      for (int i = 0; i < 4; ++i)
        __builtin_amdgcn_global_load_lds(
            (const __attribute__((address_space(1))) void*)(bSrc[i] + (kt + 1) * 32),
            (__attribute__((address_space(3))) void*)&lds[buf ^ 1][bDst[i]], 16, 0, 0);
    }

    const unsigned short* La = &lds[buf][0];
    const unsigned short* Lb = &lds[buf][2048];
    bf16x8 af[4], bv[4];
#pragma unroll
    for (int mi = 0; mi < 4; ++mi)
      af[mi] = *(const bf16x8*)(La + (mi * 16 + l15) * 32 + l16 * 8);
#pragma unroll
    for (int ni = 0; ni < 4; ++ni)
      bv[ni] = *(const bf16x8*)(Lb + (wn * 64 + ni * 16 + l15) * 32 + l16 * 8);
#pragma unroll
    for (int mi = 0; mi < 4; ++mi)
#pragma unroll
      for (int ni = 0; ni < 4; ++ni)
        acc[mi][ni] = __builtin_amdgcn_mfma_f32_16x16x32_bf16(af[mi], bv[ni],
                                                              acc[mi][ni], 0, 0, 0);

    if (nx) {                                   // convert + LDS-write after MFMA
      us8 p;
#pragma unroll
      for (int e = 0; e < 4; ++e) { p[e] = f2bf(av0[e]); p[e + 4] = f2bf(av1[e]); }
      *(us8*)&lds[buf ^ 1][aDst] = p;
    }
    __syncthreads();
    buf ^= 1;
  }

  // C-write: D col = lane&15 (n), row = (lane>>4)*4 + reg (q within 16-tile)
  unsigned short* Ao = Amat + ((size_t)batch * 4096 + qb) * 256;
#pragma unroll
  for (int mi = 0; mi < 4; ++mi)
#pragma unroll
    for (int ni = 0; ni < 4; ++ni)
#pragma unroll
      for (int j = 0; j < 4; ++j)
        Ao[(size_t)(mi * 16 + l16 * 4 + j) * 256 + wn * 64 + ni * 16 + l15] =
            f2bf(acc[mi][ni][j]);
}

// ---------------------------------------------------------------------------
// Kernel 3: out[b,c,h,w] = x[b,c,h,w] + alpha/4 * sum over valid (i,u),(j,v)
//           of A[b][i*64+j][c*16+u*4+v], where u=h+1-2i in [0,4), v likewise.
// For each h: i_hi=(h+1)>>1 (u=(h+1)&1) and i_lo=i_hi-1 (u+2), bounds-checked.
// ---------------------------------------------------------------------------
__global__ __launch_bounds__(256) void epilogue_kernel(
    const float* __restrict__ x, const unsigned short* __restrict__ Amat,
    const float* __restrict__ alpha, float* __restrict__ out) {
  int b = blockIdx.x >> 7;
  int h = blockIdx.x & 127;
  int t = threadIdx.x;
  int w = t & 127;
  int cg = t >> 7;                      // 2 groups x 8 channels

  int ihi = (h + 1) >> 1, u_hi = (h + 1) & 1;
  int jhi = (w + 1) >> 1, v_hi = (w + 1) & 1;
  bool vi_hi = (ihi <= 63), vi_lo = (ihi >= 1);
  bool vj_hi = (jhi <= 63), vj_lo = (jhi >= 1);

  float al = alpha[0] * 0.25f;
  const unsigned short* Ab = Amat + (size_t)b * 4096 * 256;

#pragma unroll
  for (int cc = 0; cc < 8; ++cc) {
    int c = cg * 8 + cc;
    float s = 0.f;
    if (vi_hi) {
      const unsigned short* Ar = Ab + (size_t)(ihi * 64) * 256 + c * 16 + u_hi * 4;
      if (vj_hi) s += bf2f(Ar[jhi * 256 + v_hi]);
      if (vj_lo) s += bf2f(Ar[(jhi - 1) * 256 + v_hi + 2]);
    }
    if (vi_lo) {
      const unsigned short* Ar = Ab + (size_t)((ihi - 1) * 64) * 256 + c * 16 + (u_hi + 2) * 4;
      if (vj_hi) s += bf2f(Ar[jhi * 256 + v_hi]);
      if (vj_lo) s += bf2f(Ar[(jhi - 1) * 256 + v_hi + 2]);
    }
    size_t xi = (((size_t)b * 16 + c) * 128 + h) * 128 + w;
    out[xi] = x[xi] + al * s;
  }
}

extern "C" void kernel_launch(void* const* d_in, const int* in_sizes, int n_in,
                              void* d_out, int out_size, void* d_ws, size_t ws_size,
                              hipStream_t stream) {
  const float* x      = (const float*)d_in[0];   // [8,16,128,128]
  const float* scores = (const float*)d_in[1];   // [8,4096,4096]
  const float* alpha  = (const float*)d_in[2];   // [1]
  float* out = (float*)d_out;                    // [8,16,128,128] fp32

  // workspace: VmatT bf16 (16 MB) | Amat bf16 (16 MB)  -> 33.5 MB total
  unsigned short* vmatT = (unsigned short*)d_ws;
  unsigned short* Amat  = (unsigned short*)((char*)d_ws + (size_t)16 * 1024 * 1024);

  prep_vmat<<<4096, 256, 0, stream>>>(x, vmatT);
  gemm_scores_vmat<<<512, 256, 0, stream>>>(scores, vmatT, Amat);
  epilogue_kernel<<<1024, 256, 0, stream>>>(x, Amat, alpha, out);
}

// Round 2
// 224.756 us; speedup vs baseline: 1.0062x; 1.0062x over previous
//
#include <hip/hip_runtime.h>
#include <hip/hip_bf16.h>

typedef float f32x4 __attribute__((ext_vector_type(4)));
typedef short bf16x8 __attribute__((ext_vector_type(8)));
typedef unsigned short us8 __attribute__((ext_vector_type(8)));

__device__ __forceinline__ unsigned short f2bf(float f) {
  union { float f; unsigned u; } v; v.f = f;
  return (unsigned short)((v.u + 0x8000u) >> 16);   // round-half-up bf16
}
__device__ __forceinline__ float bf2f(unsigned short u) {
  union { unsigned u; float f; } v; v.u = ((unsigned)u) << 16;
  return v.f;
}

// ---------------------------------------------------------------------------
// Kernel 1: VmatT[b][n][p] (bf16), n = c*16+u*4+v (256), p = pi*64+pj (4096)
// VmatT[b,n,p] = x[b, c, clamp(2*pi+u-1), clamp(2*pj+v-1)]   (replication pad)
// ---------------------------------------------------------------------------
__global__ __launch_bounds__(256) void prep_vmat(const float* __restrict__ x,
                                                 unsigned short* __restrict__ vmatT) {
  int t = blockIdx.x * 256 + threadIdx.x;     // 1,048,576 threads, 8 elems each
  int pc = t & 511;                            // p-chunk of 8
  int n  = (t >> 9) & 255;
  int b  = t >> 17;
  int c = n >> 4, u = (n >> 2) & 3, v = n & 3;
  int pi = pc >> 3;
  int pj0 = (pc & 7) << 3;
  int row = 2 * pi + u - 1;
  row = row < 0 ? 0 : (row > 127 ? 127 : row);
  const float* xr = x + ((size_t)(b * 16 + c) * 128 + row) * 128;
  us8 o;
#pragma unroll
  for (int e = 0; e < 8; ++e) {
    int col = 2 * (pj0 + e) + v - 1;
    col = col < 0 ? 0 : (col > 127 ? 127 : col);
    o[e] = f2bf(xr[col]);
  }
  *reinterpret_cast<us8*>(vmatT + (size_t)t * 8) = o;
}

// ---------------------------------------------------------------------------
// Kernel 2: A[b][q][n] (bf16) = sum_p scores[b][q][p] * VmatT[b][n][p]
// M=4096 (q), N=256 (all n in one block), K=4096. BQ=64, BK=32.
// 256 threads = 4 waves; wave w owns cols w*64..w*64+63; 4x4 16x16x32 frags.
// LDS rows are 64 B (32 bf16) = four 16-B slots; fragment reads would be
// 8-way bank conflicts (addr[6:4] = {row&1, slot}); XOR-swizzle
// slot' = slot ^ ((row>>1)&3) makes them 2-way (free). A is swizzled at the
// register-staged ds_write; B keeps a linear global_load_lds dest and the
// GLOBAL source slot is pre-swizzled (both-sides-or-neither rule).
// On reads, (row>>1)&3 == (l15>>1)&3 (rows 16-aligned per fragment), so the
// read swizzle is a per-thread constant.
// ---------------------------------------------------------------------------
__global__ __launch_bounds__(256) void gemm_scores_vmat(
    const float* __restrict__ scores,
    const unsigned short* __restrict__ vmatT,
    unsigned short* __restrict__ Amat) {
  __shared__ unsigned short lds[2][10240];   // per buf: A[64][32] then B[256][32]

  // XCD swizzle: 512 blocks, batch k's 64 blocks land on XCD k (VmatT L2-fits)
  int bid = blockIdx.x;
  int nb = ((bid & 7) << 6) | (bid >> 3);
  int batch = nb >> 6;
  int qb = (nb & 63) << 6;

  const int t = threadIdx.x;
  const int lane = t & 63;
  const int wn = t >> 6;                 // wave id = N-quadrant
  const int l15 = lane & 15, l16 = lane >> 4;

  const float* S = scores + ((size_t)batch * 4096 + qb) * 4096;
  const unsigned short* Vb = vmatT + (size_t)batch * 256 * 4096;

  // A staging: thread t -> row r=t>>2 (of 64), global slot t&3, swizzled dest
  const float* aSrc = S + (size_t)(t >> 2) * 4096 + (t & 3) * 8;
  const int aDst = (t >> 2) * 32 + (((t & 3) ^ ((t >> 3) & 3)) << 3);
  // B staging: 4 chunks/thread; LDS dest linear (global_load_lds), global
  // source slot pre-swizzled: g = (c&3) ^ ((row>>1)&3), row = c>>2.
  const unsigned short* bSrc[4];
  int bDst[4];
#pragma unroll
  for (int i = 0; i < 4; ++i) {
    int c = t + i * 256;
    int gs = (c & 3) ^ ((c >> 3) & 3);
    bSrc[i] = Vb + (size_t)(c >> 2) * 4096 + gs * 8;
    bDst[i] = 2048 + c * 8;
  }
  // read-side swizzled slot offset (elements)
  const int rsw = (l16 ^ ((l15 >> 1) & 3)) << 3;

  f32x4 acc[4][4];
#pragma unroll
  for (int mi = 0; mi < 4; ++mi)
#pragma unroll
    for (int ni = 0; ni < 4; ++ni)
      acc[mi][ni] = (f32x4){0.f, 0.f, 0.f, 0.f};

  // prologue: stage kt=0 into buf 0
  {
    f32x4 av0 = *(const f32x4*)(aSrc);
    f32x4 av1 = *(const f32x4*)(aSrc + 4);
#pragma unroll
    for (int i = 0; i < 4; ++i)
      __builtin_amdgcn_global_load_lds(
          (const __attribute__((address_space(1))) void*)(bSrc[i]),
          (__attribute__((address_space(3))) void*)&lds[0][bDst[i]], 16, 0, 0);
    us8 p;
#pragma unroll
    for (int e = 0; e < 4; ++e) { p[e] = f2bf(av0[e]); p[e + 4] = f2bf(av1[e]); }
    *(us8*)&lds[0][aDst] = p;
  }
  __syncthreads();

  int buf = 0;
  for (int kt = 0; kt < 128; ++kt) {
    f32x4 av0, av1;
    const bool nx = (kt + 1 < 128);
    if (nx) {                                   // issue next-tile loads first
      av0 = *(const f32x4*)(aSrc + (kt + 1) * 32);
      av1 = *(const f32x4*)(aSrc + (kt + 1) * 32 + 4);
#pragma unroll
      for (int i = 0; i < 4; ++i)
        __builtin_amdgcn_global_load_lds(
            (const __attribute__((address_space(1))) void*)(bSrc[i] + (kt + 1) * 32),
            (__attribute__((address_space(3))) void*)&lds[buf ^ 1][bDst[i]], 16, 0, 0);
    }

    const unsigned short* La = &lds[buf][0];
    const unsigned short* Lb = &lds[buf][2048];
    bf16x8 af[4], bv[4];
#pragma unroll
    for (int mi = 0; mi < 4; ++mi)
      af[mi] = *(const bf16x8*)(La + (mi * 16 + l15) * 32 + rsw);
#pragma unroll
    for (int ni = 0; ni < 4; ++ni)
      bv[ni] = *(const bf16x8*)(Lb + (wn * 64 + ni * 16 + l15) * 32 + rsw);
#pragma unroll
    for (int mi = 0; mi < 4; ++mi)
#pragma unroll
      for (int ni = 0; ni < 4; ++ni)
        acc[mi][ni] = __builtin_amdgcn_mfma_f32_16x16x32_bf16(af[mi], bv[ni],
                                                              acc[mi][ni], 0, 0, 0);

    if (nx) {                                   // convert + LDS-write after MFMA
      us8 p;
#pragma unroll
      for (int e = 0; e < 4; ++e) { p[e] = f2bf(av0[e]); p[e + 4] = f2bf(av1[e]); }
      *(us8*)&lds[buf ^ 1][aDst] = p;
    }
    __syncthreads();
    buf ^= 1;
  }

  // C-write: D col = lane&15 (n), row = (lane>>4)*4 + reg (q within 16-tile)
  unsigned short* Ao = Amat + ((size_t)batch * 4096 + qb) * 256;
#pragma unroll
  for (int mi = 0; mi < 4; ++mi)
#pragma unroll
    for (int ni = 0; ni < 4; ++ni)
#pragma unroll
      for (int j = 0; j < 4; ++j)
        Ao[(size_t)(mi * 16 + l16 * 4 + j) * 256 + wn * 64 + ni * 16 + l15] =
            f2bf(acc[mi][ni][j]);
}

// ---------------------------------------------------------------------------
// Kernel 3: out[b,c,h,w] = x[b,c,h,w] + alpha/4 * sum over valid (i,u),(j,v)
//           of A[b][i*64+j][c*16+u*4+v], where u=h+1-2i in [0,4), v likewise.
// ---------------------------------------------------------------------------
__global__ __launch_bounds__(256) void epilogue_kernel(
    const float* __restrict__ x, const unsigned short* __restrict__ Amat,
    const float* __restrict__ alpha, float* __restrict__ out) {
  int b = blockIdx.x >> 7;
  int h = blockIdx.x & 127;
  int t = threadIdx.x;
  int w = t & 127;
  int cg = t >> 7;                      // 2 groups x 8 channels

  int ihi = (h + 1) >> 1, u_hi = (h + 1) & 1;
  int jhi = (w + 1) >> 1, v_hi = (w + 1) & 1;
  bool vi_hi = (ihi <= 63), vi_lo = (ihi >= 1);
  bool vj_hi = (jhi <= 63), vj_lo = (jhi >= 1);

  float al = alpha[0] * 0.25f;
  const unsigned short* Ab = Amat + (size_t)b * 4096 * 256;

#pragma unroll
  for (int cc = 0; cc < 8; ++cc) {
    int c = cg * 8 + cc;
    float s = 0.f;
    if (vi_hi) {
      const unsigned short* Ar = Ab + (size_t)(ihi * 64) * 256 + c * 16 + u_hi * 4;
      if (vj_hi) s += bf2f(Ar[jhi * 256 + v_hi]);
      if (vj_lo) s += bf2f(Ar[(jhi - 1) * 256 + v_hi + 2]);
    }
    if (vi_lo) {
      const unsigned short* Ar = Ab + (size_t)((ihi - 1) * 64) * 256 + c * 16 + (u_hi + 2) * 4;
      if (vj_hi) s += bf2f(Ar[jhi * 256 + v_hi]);
      if (vj_lo) s += bf2f(Ar[(jhi - 1) * 256 + v_hi + 2]);
    }
    size_t xi = (((size_t)b * 16 + c) * 128 + h) * 128 + w;
    out[xi] = x[xi] + al * s;
  }
}

extern "C" void kernel_launch(void* const* d_in, const int* in_sizes, int n_in,
                              void* d_out, int out_size, void* d_ws, size_t ws_size,
                              hipStream_t stream) {
  const float* x      = (const float*)d_in[0];   // [8,16,128,128]
  const float* scores = (const float*)d_in[1];   // [8,4096,4096]
  const float* alpha  = (const float*)d_in[2];   // [1]
  float* out = (float*)d_out;                    // [8,16,128,128] fp32

  // workspace: VmatT bf16 (16 MB) | Amat bf16 (16 MB)
  unsigned short* vmatT = (unsigned short*)d_ws;
  unsigned short* Amat  = (unsigned short*)((char*)d_ws + (size_t)16 * 1024 * 1024);

  prep_vmat<<<4096, 256, 0, stream>>>(x, vmatT);
  gemm_scores_vmat<<<512, 256, 0, stream>>>(scores, vmatT, Amat);
  epilogue_kernel<<<1024, 256, 0, stream>>>(x, Amat, alpha, out);
}

// Round 3
// 215.703 us; speedup vs baseline: 1.0484x; 1.0420x over previous
//
#include <hip/hip_runtime.h>
#include <hip/hip_bf16.h>

typedef float f32x4 __attribute__((ext_vector_type(4)));
typedef short bf16x8 __attribute__((ext_vector_type(8)));
typedef unsigned short us8 __attribute__((ext_vector_type(8)));

__device__ __forceinline__ unsigned short f2bf(float f) {
  union { float f; unsigned u; } v; v.f = f;
  return (unsigned short)((v.u + 0x8000u) >> 16);   // round-half-up bf16
}
__device__ __forceinline__ float bf2f(unsigned short u) {
  union { unsigned u; float f; } v; v.u = ((unsigned)u) << 16;
  return v.f;
}

// ---------------------------------------------------------------------------
// Kernel 1: VmatT[b][n][p] (bf16), n = c*16+u*4+v (256), p = pi*64+pj (4096)
// ---------------------------------------------------------------------------
__global__ __launch_bounds__(256) void prep_vmat(const float* __restrict__ x,
                                                 unsigned short* __restrict__ vmatT) {
  int t = blockIdx.x * 256 + threadIdx.x;
  int pc = t & 511;
  int n  = (t >> 9) & 255;
  int b  = t >> 17;
  int c = n >> 4, u = (n >> 2) & 3, v = n & 3;
  int pi = pc >> 3;
  int pj0 = (pc & 7) << 3;
  int row = 2 * pi + u - 1;
  row = row < 0 ? 0 : (row > 127 ? 127 : row);
  const float* xr = x + ((size_t)(b * 16 + c) * 128 + row) * 128;
  us8 o;
#pragma unroll
  for (int e = 0; e < 8; ++e) {
    int col = 2 * (pj0 + e) + v - 1;
    col = col < 0 ? 0 : (col > 127 ? 127 : col);
    o[e] = f2bf(xr[col]);
  }
  *reinterpret_cast<us8*>(vmatT + (size_t)t * 8) = o;
}

// ---------------------------------------------------------------------------
// Kernel 2: A[b][q][n] (bf16) = sum_p scores[b][q][p] * VmatT[b][n][p]
// M=4096, N=256 (whole N per block), K=4096. BQ=64, BK=32, 4 waves.
// Deep-pipelined K-loop (counted vmcnt + raw s_barrier):
//   - A (scores, HBM) reg-staged 2 tiles ahead (2 named reg sets, loop
//     unrolled x2), converted fp32->bf16 + ds_write 1 tile ahead.
//   - B (VmatT, L2-resident) global_load_lds 1 tile ahead, ring-2 LDS.
//   - per iter: issue B(kt+1), issue A(kt+2), compute kt, vmcnt(2)
//     [drains A(kt+1)+B(kt+1), leaves A(kt+2) IN FLIGHT across barrier],
//     convert A(kt+1), lgkmcnt(0), raw s_barrier.
//   Issue order B-then-A is pinned with sched_barrier(0) so vmcnt counts
//   are exact. No vmcnt(0) drain in the main loop.
// ---------------------------------------------------------------------------
__global__ __launch_bounds__(256) void gemm_scores_vmat(
    const float* __restrict__ scores,
    const unsigned short* __restrict__ vmatT,
    unsigned short* __restrict__ Amat) {
  __shared__ unsigned short ldsA[2][2048];   // 64 x 32 bf16 (swizzled slots)
  __shared__ unsigned short ldsB[2][8192];   // 256 x 32 bf16 (linear dest)

  // XCD swizzle: batch k's 64 blocks land on XCD k (VmatT slice L2-fits)
  int bid = blockIdx.x;
  int nb = ((bid & 7) << 6) | (bid >> 3);
  int batch = nb >> 6;
  int qb = (nb & 63) << 6;

  const int t = threadIdx.x;
  const int lane = t & 63;
  const int wn = t >> 6;
  const int l15 = lane & 15, l16 = lane >> 4;

  const float* S = scores + ((size_t)batch * 4096 + qb) * 4096;
  const unsigned short* Vb = vmatT + (size_t)batch * 256 * 4096;

  const float* aSrc = S + (size_t)(t >> 2) * 4096 + (t & 3) * 8;
  const int aDst = (t >> 2) * 32 + (((t & 3) ^ ((t >> 3) & 3)) << 3);
  const unsigned short* bSrc[4];
  int bDst[4];
#pragma unroll
  for (int i = 0; i < 4; ++i) {
    int c = t + i * 256;
    int gs = (c & 3) ^ ((c >> 3) & 3);     // pre-swizzled global source slot
    bSrc[i] = Vb + (size_t)(c >> 2) * 4096 + gs * 8;
    bDst[i] = c * 8;
  }
  const int rsw = (l16 ^ ((l15 >> 1) & 3)) << 3;   // read-side swizzle

  f32x4 acc[4][4];
#pragma unroll
  for (int mi = 0; mi < 4; ++mi)
#pragma unroll
    for (int ni = 0; ni < 4; ++ni)
      acc[mi][ni] = (f32x4){0.f, 0.f, 0.f, 0.f};

  f32x4 r0a, r0b, r1a, r1b;   // two named A reg sets (static indexing)

#define SB __builtin_amdgcn_sched_barrier(0)
#define STAGE_B(kt, bufi)                                                     \
  {                                                                           \
    _Pragma("unroll") for (int i = 0; i < 4; ++i)                             \
        __builtin_amdgcn_global_load_lds(                                     \
            (const __attribute__((address_space(1))) void*)(bSrc[i] + (kt) * 32), \
            (__attribute__((address_space(3))) void*)&ldsB[bufi][bDst[i]],    \
            16, 0, 0);                                                        \
  }
#define LOAD_A(kt, va, vb)                                                    \
  {                                                                           \
    va = *(const f32x4*)(aSrc + (kt) * 32);                                   \
    vb = *(const f32x4*)(aSrc + (kt) * 32 + 4);                               \
  }
#define CONV_A(va, vb, bufi)                                                  \
  {                                                                           \
    us8 p;                                                                    \
    _Pragma("unroll") for (int e = 0; e < 4; ++e) {                           \
      p[e] = f2bf(va[e]); p[e + 4] = f2bf(vb[e]);                             \
    }                                                                         \
    *(us8*)&ldsA[bufi][aDst] = p;                                             \
  }
#define COMPUTE(bufi)                                                         \
  {                                                                           \
    bf16x8 af[4], bv[4];                                                      \
    _Pragma("unroll") for (int mi = 0; mi < 4; ++mi)                          \
        af[mi] = *(const bf16x8*)(&ldsA[bufi][0] + (mi * 16 + l15) * 32 + rsw); \
    _Pragma("unroll") for (int ni = 0; ni < 4; ++ni)                          \
        bv[ni] = *(const bf16x8*)(&ldsB[bufi][0] +                            \
                                  (wn * 64 + ni * 16 + l15) * 32 + rsw);      \
    _Pragma("unroll") for (int mi = 0; mi < 4; ++mi)                          \
        _Pragma("unroll") for (int ni = 0; ni < 4; ++ni)                      \
            acc[mi][ni] = __builtin_amdgcn_mfma_f32_16x16x32_bf16(            \
                af[mi], bv[ni], acc[mi][ni], 0, 0, 0);                        \
  }

  // ---- prologue: A(0)->r0, B(0)->ldsB[0], A(1)->r1; drain A0+B0; write A0
  LOAD_A(0, r0a, r0b);
  SB;
  STAGE_B(0, 0);
  SB;
  LOAD_A(1, r1a, r1b);
  SB;
  asm volatile("s_waitcnt vmcnt(2)" ::: "memory");   // A0,B0 done; A1 in flight
  SB;
  CONV_A(r0a, r0b, 0);
  asm volatile("s_waitcnt lgkmcnt(0)" ::: "memory");
  SB;
  __builtin_amdgcn_s_barrier();
  SB;

  // ---- main loop: iters 0..125, unrolled x2 (static reg-set indices)
  for (int kt = 0; kt < 126; kt += 2) {
    // even iter kt: buf 0, load A(kt+2)->r0, convert A(kt+1) from r1
    STAGE_B(kt + 1, 1);
    SB;
    LOAD_A(kt + 2, r0a, r0b);
    COMPUTE(0);
    asm volatile("s_waitcnt vmcnt(2)" ::: "memory");  // A(kt+1),B(kt+1) done
    SB;
    CONV_A(r1a, r1b, 1);
    asm volatile("s_waitcnt lgkmcnt(0)" ::: "memory");
    SB;
    __builtin_amdgcn_s_barrier();
    SB;
    // odd iter kt+1: buf 1, load A(kt+3)->r1, convert A(kt+2) from r0
    STAGE_B(kt + 2, 0);
    SB;
    LOAD_A(kt + 3, r1a, r1b);
    COMPUTE(1);
    asm volatile("s_waitcnt vmcnt(2)" ::: "memory");
    SB;
    CONV_A(r0a, r0b, 0);
    asm volatile("s_waitcnt lgkmcnt(0)" ::: "memory");
    SB;
    __builtin_amdgcn_s_barrier();
    SB;
  }

  // ---- tail: iter 126 (buf 0), iter 127 (buf 1)
  STAGE_B(127, 1);
  SB;
  COMPUTE(0);
  asm volatile("s_waitcnt vmcnt(0)" ::: "memory");    // drain A(127)+B(127)
  SB;
  CONV_A(r1a, r1b, 1);                                // A(127), loaded iter 125
  asm volatile("s_waitcnt lgkmcnt(0)" ::: "memory");
  SB;
  __builtin_amdgcn_s_barrier();
  SB;
  COMPUTE(1);

#undef SB
#undef STAGE_B
#undef LOAD_A
#undef CONV_A
#undef COMPUTE

  // C-write: D col = lane&15 (n), row = (lane>>4)*4 + reg (q within 16-tile)
  unsigned short* Ao = Amat + ((size_t)batch * 4096 + qb) * 256;
#pragma unroll
  for (int mi = 0; mi < 4; ++mi)
#pragma unroll
    for (int ni = 0; ni < 4; ++ni)
#pragma unroll
      for (int j = 0; j < 4; ++j)
        Ao[(size_t)(mi * 16 + l16 * 4 + j) * 256 + wn * 64 + ni * 16 + l15] =
            f2bf(acc[mi][ni][j]);
}

// ---------------------------------------------------------------------------
// Kernel 3: out = x + alpha/4 * gathered conv_transpose contributions
// ---------------------------------------------------------------------------
__global__ __launch_bounds__(256) void epilogue_kernel(
    const float* __restrict__ x, const unsigned short* __restrict__ Amat,
    const float* __restrict__ alpha, float* __restrict__ out) {
  int b = blockIdx.x >> 7;
  int h = blockIdx.x & 127;
  int t = threadIdx.x;
  int w = t & 127;
  int cg = t >> 7;

  int ihi = (h + 1) >> 1, u_hi = (h + 1) & 1;
  int jhi = (w + 1) >> 1, v_hi = (w + 1) & 1;
  bool vi_hi = (ihi <= 63), vi_lo = (ihi >= 1);
  bool vj_hi = (jhi <= 63), vj_lo = (jhi >= 1);

  float al = alpha[0] * 0.25f;
  const unsigned short* Ab = Amat + (size_t)b * 4096 * 256;

#pragma unroll
  for (int cc = 0; cc < 8; ++cc) {
    int c = cg * 8 + cc;
    float s = 0.f;
    if (vi_hi) {
      const unsigned short* Ar = Ab + (size_t)(ihi * 64) * 256 + c * 16 + u_hi * 4;
      if (vj_hi) s += bf2f(Ar[jhi * 256 + v_hi]);
      if (vj_lo) s += bf2f(Ar[(jhi - 1) * 256 + v_hi + 2]);
    }
    if (vi_lo) {
      const unsigned short* Ar = Ab + (size_t)((ihi - 1) * 64) * 256 + c * 16 + (u_hi + 2) * 4;
      if (vj_hi) s += bf2f(Ar[jhi * 256 + v_hi]);
      if (vj_lo) s += bf2f(Ar[(jhi - 1) * 256 + v_hi + 2]);
    }
    size_t xi = (((size_t)b * 16 + c) * 128 + h) * 128 + w;
    out[xi] = x[xi] + al * s;
  }
}

extern "C" void kernel_launch(void* const* d_in, const int* in_sizes, int n_in,
                              void* d_out, int out_size, void* d_ws, size_t ws_size,
                              hipStream_t stream) {
  const float* x      = (const float*)d_in[0];
  const float* scores = (const float*)d_in[1];
  const float* alpha  = (const float*)d_in[2];
  float* out = (float*)d_out;

  unsigned short* vmatT = (unsigned short*)d_ws;
  unsigned short* Amat  = (unsigned short*)((char*)d_ws + (size_t)16 * 1024 * 1024);

  prep_vmat<<<4096, 256, 0, stream>>>(x, vmatT);
  gemm_scores_vmat<<<512, 256, 0, stream>>>(scores, vmatT, Amat);
  epilogue_kernel<<<1024, 256, 0, stream>>>(x, Amat, alpha, out);
}

// Round 7
// 190.255 us; speedup vs baseline: 1.1887x; 1.1338x over previous
//
#include <hip/hip_runtime.h>
#include <hip/hip_bf16.h>

typedef float f32x4 __attribute__((ext_vector_type(4)));
typedef short bf16x8 __attribute__((ext_vector_type(8)));
typedef unsigned short us8 __attribute__((ext_vector_type(8)));

__device__ __forceinline__ unsigned short f2bf(float f) {
  union { float f; unsigned u; } v; v.f = f;
  return (unsigned short)((v.u + 0x8000u) >> 16);   // round-half-up bf16
}
__device__ __forceinline__ float bf2f(unsigned short u) {
  union { unsigned u; float f; } v; v.u = ((unsigned)u) << 16;
  return v.f;
}

// ---------------------------------------------------------------------------
// Kernel 1: VmatT[b][n][p] (bf16), n = c*16+u*4+v (256), p = pi*64+pj (4096)
// ---------------------------------------------------------------------------
__global__ __launch_bounds__(256) void prep_vmat(const float* __restrict__ x,
                                                 unsigned short* __restrict__ vmatT) {
  int t = blockIdx.x * 256 + threadIdx.x;
  int pc = t & 511;
  int n  = (t >> 9) & 255;
  int b  = t >> 17;
  int c = n >> 4, u = (n >> 2) & 3, v = n & 3;
  int pi = pc >> 3;
  int pj0 = (pc & 7) << 3;
  int row = 2 * pi + u - 1;
  row = row < 0 ? 0 : (row > 127 ? 127 : row);
  const float* xr = x + ((size_t)(b * 16 + c) * 128 + row) * 128;
  us8 o;
#pragma unroll
  for (int e = 0; e < 8; ++e) {
    int col = 2 * (pj0 + e) + v - 1;
    col = col < 0 ? 0 : (col > 127 ? 127 : col);
    o[e] = f2bf(xr[col]);
  }
  *reinterpret_cast<us8*>(vmatT + (size_t)t * 8) = o;
}

// ---------------------------------------------------------------------------
// Kernel 2: A[b][q][n] (bf16) = sum_p scores[b][q][p] * VmatT[b][n][p]
// M=4096, N=256, K=4096. BQ=64, BK=64 -> 64 K-TILES (R4/R5/R6 bug: ran 32).
// 4 waves, M-split: wave w owns q-rows 16w..16w+15, all 256 n.
// LDS = B only: 2 x 32 KB ring (64 KB static).
//  - A (scores, HBM): each lane loads ITS OWN MFMA fragment directly from
//    global (row l15, k=l16*8). Reg-staged 2 tiles ahead (rE/rO named sets);
//    CONV extracts to fe/fo BEFORE the set is overwritten (R5 bug fix).
//  - B (VmatT, L2-resident): global_load_lds 16B, 1 tile ahead, ring-2;
//    global source slot pre-swizzled gs = slot ^ (row&7); reads same XOR.
//  - per iter: CONV; issue B(kt+1) [8 vm]; issue A(kt+2) [4 vm]; MFMAs;
//    vmcnt(4) leaves A(kt+2) in flight across the single barrier.
//  - K-phase rotation: block starts at tile (qbi&63) -> co-resident blocks
//    touch different 256-B column offsets (DRAM page/channel spread).
//  - uniform 64 iters; tail prefetches wrap (&63), kept alive by trailing
//    asm so the vmcnt FIFO accounting stays exact.
// ---------------------------------------------------------------------------
__global__ __launch_bounds__(256) void gemm_scores_vmat(
    const float* __restrict__ scores,
    const unsigned short* __restrict__ vmatT,
    unsigned short* __restrict__ Amat) {
  __shared__ unsigned short ldsB[2][16384];   // 256 rows x 64 bf16, x2

  int bid = blockIdx.x;
  int nb = ((bid & 7) << 6) | (bid >> 3);     // batch = XCD id
  int batch = nb >> 6;
  int qb = (nb & 63) << 6;
  const int phase = (bid >> 3) & 63;          // full-range K rotation

  const int t = threadIdx.x;
  const int lane = t & 63;
  const int wq = t >> 6;                      // wave id = M-quadrant
  const int l15 = lane & 15, l16 = lane >> 4;

  // A: per-lane fragment base (row = qb + wq*16 + l15, k-offset l16*8)
  const float* aLane =
      scores + ((size_t)(batch * 4096 + qb + wq * 16 + l15)) * 4096 + l16 * 8;
  const unsigned short* Vb = vmatT + (size_t)batch * 256 * 4096;

  // B staging: 8 chunks/thread; LDS dest linear, global source slot swizzled
  const unsigned short* bSrc[8];
  int bDst[8];
#pragma unroll
  for (int i = 0; i < 8; ++i) {
    int c = t + i * 256;
    int gs = (c & 7) ^ ((c >> 3) & 7);
    bSrc[i] = Vb + (size_t)(c >> 3) * 4096 + gs * 8;
    bDst[i] = c * 8;
  }
  const int pos0 = (l16 ^ (l15 & 7)) << 3;    // swizzled slot, ks=0 (elems)

  f32x4 acc[16];
#pragma unroll
  for (int ni = 0; ni < 16; ++ni) acc[ni] = (f32x4){0.f, 0.f, 0.f, 0.f};

  f32x4 rE[4], rO[4];     // two named A reg sets (static indexing)
  bf16x8 fe0, fe1, fo0, fo1;

#define SB __builtin_amdgcn_sched_barrier(0)
#define STAGE_B(kt, bufi)                                                     \
  {                                                                           \
    int kp_ = ((kt) + phase) & 63;                                            \
    _Pragma("unroll") for (int i = 0; i < 8; ++i)                             \
        __builtin_amdgcn_global_load_lds(                                     \
            (const __attribute__((address_space(1))) void*)(bSrc[i] + (size_t)kp_ * 64), \
            (__attribute__((address_space(3))) void*)&ldsB[bufi][bDst[i]],    \
            16, 0, 0);                                                        \
  }
#define LOAD_A(kt, rr)                                                        \
  {                                                                           \
    int kp_ = ((kt) + phase) & 63;                                            \
    const float* ap_ = aLane + (size_t)kp_ * 64;                              \
    rr[0] = *(const f32x4*)(ap_);                                             \
    rr[1] = *(const f32x4*)(ap_ + 4);                                         \
    rr[2] = *(const f32x4*)(ap_ + 32);                                        \
    rr[3] = *(const f32x4*)(ap_ + 36);                                        \
  }
#define CONV(rr, fa0, fa1)                                                    \
  {                                                                           \
    _Pragma("unroll") for (int e = 0; e < 4; ++e) {                           \
      fa0[e] = (short)f2bf(rr[0][e]); fa0[e + 4] = (short)f2bf(rr[1][e]);     \
      fa1[e] = (short)f2bf(rr[2][e]); fa1[e + 4] = (short)f2bf(rr[3][e]);     \
    }                                                                         \
  }
#define MFMAS(fa0, fa1, bufi)                                                 \
  {                                                                           \
    _Pragma("unroll") for (int ni = 0; ni < 16; ++ni) {                       \
      bf16x8 bv = *(const bf16x8*)(&ldsB[bufi][0] +                           \
                                   (ni * 16 + l15) * 64 + pos0);              \
      acc[ni] = __builtin_amdgcn_mfma_f32_16x16x32_bf16(fa0, bv, acc[ni],     \
                                                        0, 0, 0);             \
    }                                                                         \
    _Pragma("unroll") for (int ni = 0; ni < 16; ++ni) {                       \
      bf16x8 bv = *(const bf16x8*)(&ldsB[bufi][0] +                           \
                                   (ni * 16 + l15) * 64 + (pos0 ^ 32));      \
      acc[ni] = __builtin_amdgcn_mfma_f32_16x16x32_bf16(fa1, bv, acc[ni],     \
                                                        0, 0, 0);             \
    }                                                                         \
  }

  // ---- prologue: A(0)->rE, B(0)->buf0, A(1)->rO; keep A(1) in flight
  LOAD_A(0, rE);
  SB;
  STAGE_B(0, 0);
  SB;
  LOAD_A(1, rO);
  SB;
  asm volatile("s_waitcnt vmcnt(4)" ::: "memory");  // A0,B0 landed
  SB;
  __builtin_amdgcn_s_barrier();
  SB;

  // ---- main loop: 64 uniform iters, unrolled x2 (static reg-set roles)
  for (int kt = 0; kt < 64; kt += 2) {
    // EVEN: consume rE=A(kt), buf0=B(kt)
    CONV(rE, fe0, fe1);          // extract BEFORE reload
    SB;
    STAGE_B(kt + 1, 1);
    SB;
    LOAD_A(kt + 2, rE);
    SB;
    MFMAS(fe0, fe1, 0);
    asm volatile("s_waitcnt vmcnt(4)" ::: "memory");  // A(kt+1),B(kt+1) landed
    SB;
    __builtin_amdgcn_s_barrier();
    SB;
    // ODD: consume rO=A(kt+1), buf1=B(kt+1)
    CONV(rO, fo0, fo1);
    SB;
    STAGE_B(kt + 2, 0);
    SB;
    LOAD_A(kt + 3, rO);
    SB;
    MFMAS(fo0, fo1, 1);
    asm volatile("s_waitcnt vmcnt(4)" ::: "memory");
    SB;
    __builtin_amdgcn_s_barrier();
    SB;
  }

  // keep tail prefetches live so the loop's vmcnt FIFO accounting is exact
  asm volatile("" ::"v"(rE[0][0]), "v"(rE[1][0]), "v"(rE[2][0]), "v"(rE[3][0]),
               "v"(rO[0][0]), "v"(rO[1][0]), "v"(rO[2][0]), "v"(rO[3][0]));

#undef SB
#undef STAGE_B
#undef LOAD_A
#undef CONV
#undef MFMAS

  // C-write: wave wq owns q-rows qb+wq*16..+15; row=(l16*4+j), col=l15 per ni
  unsigned short* Ao = Amat + ((size_t)(batch * 4096 + qb + wq * 16)) * 256;
#pragma unroll
  for (int ni = 0; ni < 16; ++ni)
#pragma unroll
    for (int j = 0; j < 4; ++j)
      Ao[(size_t)(l16 * 4 + j) * 256 + ni * 16 + l15] = f2bf(acc[ni][j]);
}

// ---------------------------------------------------------------------------
// Kernel 3: out = x + alpha/4 * gathered conv_transpose contributions
// ---------------------------------------------------------------------------
__global__ __launch_bounds__(256) void epilogue_kernel(
    const float* __restrict__ x, const unsigned short* __restrict__ Amat,
    const float* __restrict__ alpha, float* __restrict__ out) {
  int b = blockIdx.x >> 7;
  int h = blockIdx.x & 127;
  int t = threadIdx.x;
  int w = t & 127;
  int cg = t >> 7;

  int ihi = (h + 1) >> 1, u_hi = (h + 1) & 1;
  int jhi = (w + 1) >> 1, v_hi = (w + 1) & 1;
  bool vi_hi = (ihi <= 63), vi_lo = (ihi >= 1);
  bool vj_hi = (jhi <= 63), vj_lo = (jhi >= 1);

  float al = alpha[0] * 0.25f;
  const unsigned short* Ab = Amat + (size_t)b * 4096 * 256;

#pragma unroll
  for (int cc = 0; cc < 8; ++cc) {
    int c = cg * 8 + cc;
    float s = 0.f;
    if (vi_hi) {
      const unsigned short* Ar = Ab + (size_t)(ihi * 64) * 256 + c * 16 + u_hi * 4;
      if (vj_hi) s += bf2f(Ar[jhi * 256 + v_hi]);
      if (vj_lo) s += bf2f(Ar[(jhi - 1) * 256 + v_hi + 2]);
    }
    if (vi_lo) {
      const unsigned short* Ar = Ab + (size_t)((ihi - 1) * 64) * 256 + c * 16 + (u_hi + 2) * 4;
      if (vj_hi) s += bf2f(Ar[jhi * 256 + v_hi]);
      if (vj_lo) s += bf2f(Ar[(jhi - 1) * 256 + v_hi + 2]);
    }
    size_t xi = (((size_t)b * 16 + c) * 128 + h) * 128 + w;
    out[xi] = x[xi] + al * s;
  }
}

extern "C" void kernel_launch(void* const* d_in, const int* in_sizes, int n_in,
                              void* d_out, int out_size, void* d_ws, size_t ws_size,
                              hipStream_t stream) {
  const float* x      = (const float*)d_in[0];
  const float* scores = (const float*)d_in[1];
  const float* alpha  = (const float*)d_in[2];
  float* out = (float*)d_out;

  unsigned short* vmatT = (unsigned short*)d_ws;
  unsigned short* Amat  = (unsigned short*)((char*)d_ws + (size_t)16 * 1024 * 1024);

  prep_vmat<<<4096, 256, 0, stream>>>(x, vmatT);
  gemm_scores_vmat<<<512, 256, 0, stream>>>(scores, vmatT, Amat);
  epilogue_kernel<<<1024, 256, 0, stream>>>(x, Amat, alpha, out);
}